// Round 1
// 1358.695 us; speedup vs baseline: 1.0707x; 1.0707x over previous
//
#include <hip/hip_runtime.h>
#include <hip/hip_bf16.h>

#define L_LAYERS 4
#define D_MODEL 768
#define SEQ 1024
#define BATCH 2
#define NHEAD 12
#define HDIM 64
#define DFF_DIM 3072
#define VOCAB 32000
#define MROWS (BATCH*SEQ)                      // 2048
#define QKV_PLANE (NHEAD*BATCH*SEQ*HDIM)       // 24*1024*64 = 1572864

typedef __attribute__((ext_vector_type(8))) short bfrag8;   // 8 bf16 in 4 VGPRs
typedef __attribute__((ext_vector_type(4))) float facc4;    // MFMA accumulator

#define EPI_PLAIN 0
#define EPI_BIAS 1
#define EPI_GELU_BF16 2
#define EPI_QKV 3

__device__ __forceinline__ void gld_lds16(const __hip_bfloat16* g, __hip_bfloat16* l) {
    __builtin_amdgcn_global_load_lds((const __attribute__((address_space(1))) void*)g,
                                     (__attribute__((address_space(3))) void*)l, 16, 0, 0);
}

// ---------------- weight transpose + cast: src fp32 [K,N] -> dst bf16 [N,K] ----------------
__global__ __launch_bounds__(256) void transpose_cast(
    const float* __restrict__ src, __hip_bfloat16* __restrict__ dst,
    const int K, const int N, const long sL, const long dL)
{
    __shared__ float tile[32][33];
    const int z = blockIdx.z;
    const float* s = src + (long)z * sL;
    __hip_bfloat16* d = dst + (long)z * dL;
    const int bx = blockIdx.x * 32;   // N block
    const int by = blockIdx.y * 32;   // K block
    const int tx = threadIdx.x, ty = threadIdx.y;
    #pragma unroll
    for (int r = 0; r < 4; ++r)
        tile[ty + r*8][tx] = s[(long)(by + ty + r*8) * N + bx + tx];
    __syncthreads();
    #pragma unroll
    for (int r = 0; r < 4; ++r)
        d[(long)(bx + ty + r*8) * K + by + tx] = __float2bfloat16(tile[tx][ty + r*8]);
}

// ---------------- embedding + sinusoidal PE -> h fp32, hb bf16 ----------------
__global__ __launch_bounds__(256) void embed_k(
    const int* __restrict__ xids, const float* __restrict__ emb,
    float* __restrict__ h, __hip_bfloat16* __restrict__ hb)
{
    const int row = blockIdx.x, t = threadIdx.x;
    const int tok = xids[row];
    const int spos = row & (SEQ - 1);
    const long base = (long)row * D_MODEL;
    const long ebase = (long)tok * D_MODEL;
    #pragma unroll
    for (int j = 0; j < 3; ++j) {
        const int d = j*256 + t;
        const int i = d >> 1;
        const float ang = (float)spos * expf(-(float)(2*i) * (9.210340371976184f / 768.0f));
        const float pe = (d & 1) ? cosf(ang) : sinf(ang);
        const float v = emb[ebase + d] + pe;
        h[base + d] = v;
        hb[base + d] = __float2bfloat16(v);
    }
}

// ---------------- residual add (sum of nplanes partial deltas) + LayerNorm ----------------
__global__ __launch_bounds__(256) void ln_residual(
    float* __restrict__ h, __hip_bfloat16* __restrict__ hb,
    const float* __restrict__ delta,
    const float* __restrict__ sc, const float* __restrict__ bi,
    const int nplanes)
{
    const int row = blockIdx.x, t = threadIdx.x;
    const long base = (long)row * D_MODEL;
    float x[3];
    float s1 = 0.f, s2 = 0.f;
    #pragma unroll
    for (int j = 0; j < 3; ++j) {
        const int d = j*256 + t;
        float v = h[base + d];
        for (int p = 0; p < nplanes; ++p)
            v += delta[(long)p * MROWS * D_MODEL + base + d];
        x[j] = v; s1 += v; s2 += v*v;
    }
    #pragma unroll
    for (int off = 32; off >= 1; off >>= 1) {
        s1 += __shfl_xor(s1, off);
        s2 += __shfl_xor(s2, off);
    }
    __shared__ float r1[4], r2[4];
    const int wv = t >> 6;
    if ((t & 63) == 0) { r1[wv] = s1; r2[wv] = s2; }
    __syncthreads();
    s1 = r1[0] + r1[1] + r1[2] + r1[3];
    s2 = r2[0] + r2[1] + r2[2] + r2[3];
    const float mean = s1 * (1.0f/768.0f);
    const float var  = s2 * (1.0f/768.0f) - mean*mean;
    const float inv  = rsqrtf(var + 1e-5f);
    #pragma unroll
    for (int j = 0; j < 3; ++j) {
        const int d = j*256 + t;
        const float y = (x[j] - mean) * inv * sc[d] + bi[d];
        h[base + d] = y;
        hb[base + d] = __float2bfloat16(y);
    }
}

// ---------------- generic bf16 MFMA GEMM: C[M,N] = A[M,K] * Bt[N,K]^T (+epilogue) ----------------
// 128x128 tile, BK=32, 256 threads (4 waves, 2x2), m97-style global_load_lds staging.
// Block remap: bijective XCD chunking (m204) + M-fastest decomposition so blocks within an
// XCD chunk share B-stripes (196 KB) while the A panel (3 MB @ M=2048) stays L2-resident.
// Split-K via blockIdx.z: chunk z computes K-range [z*Kc,(z+1)*Kc) and writes fp32 partial
// plane z (EPI_PLAIN / EPI_BIAS only); consumer sums planes. Bias added by plane 0 only.
__global__ __launch_bounds__(256) void gemm_bt(
    const __hip_bfloat16* __restrict__ A,
    const __hip_bfloat16* __restrict__ Bt,
    const float* __restrict__ bias,
    float* __restrict__ outf,
    __hip_bfloat16* __restrict__ outb,
    const int N, const int K, const int epi)
{
    __shared__ __hip_bfloat16 As[128*32];
    __shared__ __hip_bfloat16 Bs[128*32];
    const int tid = threadIdx.x;
    const int lane = tid & 63, wv = tid >> 6;

    // --- block remap ---
    const int nwg  = gridDim.x * gridDim.y;
    const int orig = blockIdx.y * gridDim.x + blockIdx.x;
    const int qq = nwg >> 3, rr = nwg & 7;
    const int xcd = orig & 7, lin = orig >> 3;
    const int wgid = (xcd < rr ? xcd * (qq + 1) : rr * (qq + 1) + (xcd - rr) * qq) + lin;
    const int bmi = wgid % gridDim.y;           // M-block (fastest within chunk)
    const int bni = wgid / gridDim.y;           // N-block
    const int bm = bmi * 128, bn = bni * 128;

    const int wm = (wv >> 1) * 64, wn = (wv & 1) * 64;
    const int fr = lane & 15, fq = lane >> 4;

    // --- split-K ---
    const int Kc = K / gridDim.z;
    const long zoff = (long)blockIdx.z * Kc;

    facc4 acc[4][4];
    #pragma unroll
    for (int i = 0; i < 4; ++i)
        #pragma unroll
        for (int j = 0; j < 4; ++j) { facc4 z = {0.f,0.f,0.f,0.f}; acc[i][j] = z; }

    // staging: wave wv owns tile rows [wv*32, wv*32+32), 2 issues of 16 rows each
    const int srow = wv*32 + (lane >> 2);
    const int scol = (lane & 3) * 8;
    const __hip_bfloat16* Ag = A  + (long)(bm + srow) * K + scol + zoff;
    const __hip_bfloat16* Bg = Bt + (long)(bn + srow) * K + scol + zoff;
    __hip_bfloat16* Asw = As + wv*1024;
    __hip_bfloat16* Bsw = Bs + wv*1024;

    for (int k0 = 0; k0 < Kc; k0 += 32) {
        __syncthreads();
        gld_lds16(Ag + k0,                 Asw);
        gld_lds16(Ag + k0 + (long)16*K,    Asw + 512);
        gld_lds16(Bg + k0,                 Bsw);
        gld_lds16(Bg + k0 + (long)16*K,    Bsw + 512);
        __syncthreads();
        bfrag8 af[4], bf[4];
        #pragma unroll
        for (int i = 0; i < 4; ++i) af[i] = *(const bfrag8*)(As + (wm + i*16 + fr)*32 + fq*8);
        #pragma unroll
        for (int j = 0; j < 4; ++j) bf[j] = *(const bfrag8*)(Bs + (wn + j*16 + fr)*32 + fq*8);
        #pragma unroll
        for (int i = 0; i < 4; ++i)
            #pragma unroll
            for (int j = 0; j < 4; ++j)
                acc[i][j] = __builtin_amdgcn_mfma_f32_16x16x32_bf16(af[i], bf[j], acc[i][j], 0, 0, 0);
    }

    // epilogue: C elem (i,j,r): row = bm+wm+i*16+fq*4+r, col = bn+wn+j*16+fr
    if (epi == EPI_QKV) {
        __hip_bfloat16* qo = outb;
        __hip_bfloat16* ko = outb + QKV_PLANE;
        __hip_bfloat16* vo = outb + 2*QKV_PLANE;
        #pragma unroll
        for (int i = 0; i < 4; ++i) {
            #pragma unroll
            for (int j = 0; j < 4; ++j) {
                const int gn = bn + wn + j*16 + fr;
                const int which = gn / D_MODEL;
                const int nn = gn - which * D_MODEL;
                const int hh = nn >> 6, dd = nn & 63;
                #pragma unroll
                for (int r = 0; r < 4; ++r) {
                    const int gm = bm + wm + i*16 + fq*4 + r;
                    const int bidx = gm >> 10, si = gm & (SEQ-1);
                    const long bh = (long)bidx * NHEAD + hh;
                    const __hip_bfloat16 bv = __float2bfloat16(acc[i][j][r]);
                    if (which == 0)      qo[(bh*SEQ + si)*HDIM + dd] = bv;   // Q planar [bh][s][d]
                    else if (which == 1) ko[(bh*SEQ + si)*HDIM + dd] = bv;   // K planar [bh][s][d]
                    else                 vo[(bh*HDIM + dd)*SEQ + si] = bv;   // V transposed [bh][d][s]
                }
            }
        }
    } else if (epi == EPI_GELU_BF16) {
        #pragma unroll
        for (int i = 0; i < 4; ++i)
            #pragma unroll
            for (int j = 0; j < 4; ++j) {
                const int gn = bn + wn + j*16 + fr;
                const float bb = bias[gn];
                #pragma unroll
                for (int r = 0; r < 4; ++r) {
                    const int gm = bm + wm + i*16 + fq*4 + r;
                    const float v = acc[i][j][r] + bb;
                    const float g = 0.5f * v * (1.0f + erff(v * 0.70710678118f));
                    outb[(long)gm * N + gn] = __float2bfloat16(g);
                }
            }
    } else if (epi == EPI_BIAS) {
        float* outz = outf + (long)blockIdx.z * (long)(gridDim.y * 128) * N;
        #pragma unroll
        for (int i = 0; i < 4; ++i)
            #pragma unroll
            for (int j = 0; j < 4; ++j) {
                const int gn = bn + wn + j*16 + fr;
                const float bb = (blockIdx.z == 0) ? bias[gn] : 0.f;
                #pragma unroll
                for (int r = 0; r < 4; ++r) {
                    const int gm = bm + wm + i*16 + fq*4 + r;
                    outz[(long)gm * N + gn] = acc[i][j][r] + bb;
                }
            }
    } else {
        float* outz = outf + (long)blockIdx.z * (long)(gridDim.y * 128) * N;
        #pragma unroll
        for (int i = 0; i < 4; ++i)
            #pragma unroll
            for (int j = 0; j < 4; ++j) {
                const int gn = bn + wn + j*16 + fr;
                #pragma unroll
                for (int r = 0; r < 4; ++r) {
                    const int gm = bm + wm + i*16 + fq*4 + r;
                    outz[(long)gm * N + gn] = acc[i][j][r];
                }
            }
    }
}

// ---------------- fused causal attention (strict mask k<q, exp/(sum+1e-9) softmax) ----------------
// grid (S/64, B*H); block 256 = 4 waves; wave w owns q rows [q0+16w, q0+16w+16)
#define KS_STRIDE 80   // 32 k-rows x 64 d, padded (160B rows, 16B aligned)
#define VS_STRIDE 40   // 64 d-rows x 32 k, padded (80B rows)
#define PS_STRIDE 40   // per-wave P: 16 q x 32 k, padded
__global__ __launch_bounds__(256) void attn_flash(
    const __hip_bfloat16* __restrict__ Q,   // [BH][S][64]
    const __hip_bfloat16* __restrict__ Kp,  // [BH][S][64]
    const __hip_bfloat16* __restrict__ Vt,  // [BH][64][S]
    __hip_bfloat16* __restrict__ avo)       // [2048][768] bf16 (A for Wo GEMM)
{
    __shared__ __hip_bfloat16 Ks[32*KS_STRIDE];
    __shared__ __hip_bfloat16 Vs[64*VS_STRIDE];
    __shared__ __hip_bfloat16 Ps[4][16*PS_STRIDE];
    const int tid = threadIdx.x;
    const int lane = tid & 63, wv = tid >> 6;
    const int fr = lane & 15, fq = lane >> 4;
    const int q0 = blockIdx.x * 64;
    const int bh = blockIdx.y;
    const int qrow = q0 + wv*16;

    // Q fragments straight from global (A layout: m=fr, k=fq*8+j)
    const __hip_bfloat16* qp = Q + ((long)bh*SEQ + qrow + fr)*HDIM + fq*8;
    const bfrag8 aq0 = *(const bfrag8*)(qp);
    const bfrag8 aq1 = *(const bfrag8*)(qp + 32);

    facc4 accv[4];
    #pragma unroll
    for (int n = 0; n < 4; ++n) { facc4 z = {0.f,0.f,0.f,0.f}; accv[n] = z; }
    float denom[4] = {0.f, 0.f, 0.f, 0.f};

    const __hip_bfloat16* kg = Kp + ((long)bh*SEQ + (tid>>3))*HDIM + (tid&7)*8;
    const __hip_bfloat16* vg = Vt + ((long)bh*HDIM + (tid>>2))*SEQ + (tid&3)*8;
    __hip_bfloat16* ksw = Ks + (tid>>3)*KS_STRIDE + (tid&7)*8;
    __hip_bfloat16* vsw = Vs + (tid>>2)*VS_STRIDE + (tid&3)*8;

    const int kend = q0 + 64;   // strict mask: max needed k is q0+62
    for (int k0 = 0; k0 < kend; k0 += 32) {
        __syncthreads();
        *(bfrag8*)ksw = *(const bfrag8*)(kg + (long)k0 * HDIM);
        *(bfrag8*)vsw = *(const bfrag8*)(vg + k0);
        __syncthreads();
        #pragma unroll
        for (int t = 0; t < 2; ++t) {
            const int koff = t*16;
            const bfrag8 bk0 = *(const bfrag8*)(Ks + (koff + fr)*KS_STRIDE + fq*8);
            const bfrag8 bk1 = *(const bfrag8*)(Ks + (koff + fr)*KS_STRIDE + 32 + fq*8);
            facc4 sc = {0.f,0.f,0.f,0.f};
            sc = __builtin_amdgcn_mfma_f32_16x16x32_bf16(aq0, bk0, sc, 0, 0, 0);
            sc = __builtin_amdgcn_mfma_f32_16x16x32_bf16(aq1, bk1, sc, 0, 0, 0);
            const int ki = k0 + koff + fr;
            #pragma unroll
            for (int r = 0; r < 4; ++r) {
                const int qi = qrow + fq*4 + r;
                const float e = (ki < qi) ? __expf(sc[r] * 0.125f) : 0.f;
                denom[r] += e;
                Ps[wv][(fq*4 + r)*PS_STRIDE + koff + fr] = __float2bfloat16(e);
            }
        }
        __syncthreads();
        const bfrag8 ap = *(const bfrag8*)(&Ps[wv][fr*PS_STRIDE + fq*8]);
        #pragma unroll
        for (int n = 0; n < 4; ++n) {
            const bfrag8 bv = *(const bfrag8*)(Vs + (n*16 + fr)*VS_STRIDE + fq*8);
            accv[n] = __builtin_amdgcn_mfma_f32_16x16x32_bf16(ap, bv, accv[n], 0, 0, 0);
        }
    }

    // row sums: reduce denom across the 16 lanes of each row group
    #pragma unroll
    for (int r = 0; r < 4; ++r) {
        #pragma unroll
        for (int off = 1; off < 16; off <<= 1) denom[r] += __shfl_xor(denom[r], off);
    }
    const int bidx = bh / NHEAD, hh = bh % NHEAD;
    #pragma unroll
    for (int n = 0; n < 4; ++n) {
        #pragma unroll
        for (int r = 0; r < 4; ++r) {
            const int qi = qrow + fq*4 + r;
            const int dd = n*16 + fr;
            const float o = accv[n][r] / (denom[r] + 1e-9f);
            avo[((long)(bidx*SEQ + qi))*D_MODEL + hh*HDIM + dd] = __float2bfloat16(o);
        }
    }
}

extern "C" void kernel_launch(void* const* d_in, const int* in_sizes, int n_in,
                              void* d_out, int out_size, void* d_ws, size_t ws_size,
                              hipStream_t stream) {
    const int*   x    = (const int*)d_in[0];
    const float* emb  = (const float*)d_in[1];
    const float* Wq   = (const float*)d_in[2];
    const float* Wk   = (const float*)d_in[3];
    const float* Wv   = (const float*)d_in[4];
    const float* Wo   = (const float*)d_in[5];
    const float* ln1s = (const float*)d_in[6];
    const float* ln1b = (const float*)d_in[7];
    const float* W1   = (const float*)d_in[8];
    const float* b1   = (const float*)d_in[9];
    const float* W2   = (const float*)d_in[10];
    const float* b2   = (const float*)d_in[11];
    const float* ln2s = (const float*)d_in[12];
    const float* ln2b = (const float*)d_in[13];
    const float* lmW  = (const float*)d_in[14];
    const float* lmb  = (const float*)d_in[15];
    float* out = (float*)d_out;

    char* wsp = (char*)d_ws;
    size_t off = 0;
    auto take = [&](size_t bytes) -> char* {
        char* p = wsp + off;
        off += (bytes + 255) & ~(size_t)255;
        return p;
    };
    __hip_bfloat16* wqkvT = (__hip_bfloat16*)take((size_t)L_LAYERS*2304*768*2); // fused [2304,768] per layer
    __hip_bfloat16* woT   = (__hip_bfloat16*)take((size_t)L_LAYERS*768*768*2);
    __hip_bfloat16* w1T   = (__hip_bfloat16*)take((size_t)L_LAYERS*3072*768*2);
    __hip_bfloat16* w2T   = (__hip_bfloat16*)take((size_t)L_LAYERS*768*3072*2);
    __hip_bfloat16* lmT   = (__hip_bfloat16*)take((size_t)VOCAB*768*2);
    float*          hbuf  = (float*)take((size_t)MROWS*D_MODEL*4);
    __hip_bfloat16* hb    = (__hip_bfloat16*)take((size_t)MROWS*D_MODEL*2);
    __hip_bfloat16* qkvb  = (__hip_bfloat16*)take((size_t)3*QKV_PLANE*2);
    __hip_bfloat16* avb   = (__hip_bfloat16*)take((size_t)MROWS*D_MODEL*2);
    __hip_bfloat16* ffb   = (__hip_bfloat16*)take((size_t)MROWS*DFF_DIM*2);
    float*          tmp   = (float*)take((size_t)2*MROWS*D_MODEL*4);   // 2 split-K planes

    dim3 tb(32, 8);
    transpose_cast<<<dim3(24,24,4), tb, 0, stream>>>(Wq, wqkvT,              768, 768, (long)768*768, (long)2304*768);
    transpose_cast<<<dim3(24,24,4), tb, 0, stream>>>(Wk, wqkvT + 768*768,    768, 768, (long)768*768, (long)2304*768);
    transpose_cast<<<dim3(24,24,4), tb, 0, stream>>>(Wv, wqkvT + 2*768*768,  768, 768, (long)768*768, (long)2304*768);
    transpose_cast<<<dim3(24,24,4), tb, 0, stream>>>(Wo, woT,                768, 768, (long)768*768, (long)768*768);
    transpose_cast<<<dim3(96,24,4), tb, 0, stream>>>(W1, w1T,                768, 3072, (long)768*3072, (long)3072*768);
    transpose_cast<<<dim3(24,96,4), tb, 0, stream>>>(W2, w2T,                3072, 768, (long)3072*768, (long)768*3072);
    transpose_cast<<<dim3(1000,24,1), tb, 0, stream>>>(lmW, lmT,             768, VOCAB, 0, 0);

    embed_k<<<MROWS, 256, 0, stream>>>(x, emb, hbuf, hb);

    for (int l = 0; l < L_LAYERS; ++l) {
        gemm_bt<<<dim3(18,16), 256, 0, stream>>>(hb, wqkvT + (size_t)l*2304*768, nullptr,
                                                 nullptr, qkvb, 2304, 768, EPI_QKV);
        attn_flash<<<dim3(16,24), 256, 0, stream>>>(qkvb, qkvb + QKV_PLANE, qkvb + 2*QKV_PLANE, avb);
        // Wo: split-K x2 (96 -> 192 wg) writing 2 fp32 partial planes
        gemm_bt<<<dim3(6,16,2), 256, 0, stream>>>(avb, woT + (size_t)l*768*768, nullptr,
                                                  tmp, nullptr, 768, 768, EPI_PLAIN);
        ln_residual<<<MROWS, 256, 0, stream>>>(hbuf, hb, tmp, ln1s + l*768, ln1b + l*768, 2);
        gemm_bt<<<dim3(24,16), 256, 0, stream>>>(hb, w1T + (size_t)l*3072*768, b1 + l*DFF_DIM,
                                                 nullptr, ffb, DFF_DIM, 768, EPI_GELU_BF16);
        // FF2: split-K x2 (96 -> 192 wg, K=1536 each) writing 2 fp32 partial planes
        gemm_bt<<<dim3(6,16,2), 256, 0, stream>>>(ffb, w2T + (size_t)l*768*3072, b2 + l*768,
                                                  tmp, nullptr, 768, DFF_DIM, EPI_BIAS);
        ln_residual<<<MROWS, 256, 0, stream>>>(hbuf, hb, tmp, ln2s + l*768, ln2b + l*768, 2);
    }
    gemm_bt<<<dim3(250,16), 256, 0, stream>>>(hb, lmT, lmb, out, nullptr, VOCAB, 768, EPI_BIAS);
}

// Round 2
// 1163.676 us; speedup vs baseline: 1.2501x; 1.1676x over previous
//
#include <hip/hip_runtime.h>
#include <hip/hip_bf16.h>

#define L_LAYERS 4
#define D_MODEL 768
#define SEQ 1024
#define BATCH 2
#define NHEAD 12
#define HDIM 64
#define DFF_DIM 3072
#define VOCAB 32000
#define MROWS (BATCH*SEQ)                      // 2048
#define QKV_PLANE (NHEAD*BATCH*SEQ*HDIM)       // 24*1024*64 = 1572864

typedef __attribute__((ext_vector_type(8))) short bfrag8;   // 8 bf16 in 4 VGPRs
typedef __attribute__((ext_vector_type(4))) float facc4;    // MFMA accumulator

#define EPI_PLAIN 0
#define EPI_BIAS 1
#define EPI_GELU_BF16 2
#define EPI_QKV 3

__device__ __forceinline__ void gld_lds16(const __hip_bfloat16* g, __hip_bfloat16* l) {
    __builtin_amdgcn_global_load_lds((const __attribute__((address_space(1))) void*)g,
                                     (__attribute__((address_space(3))) void*)l, 16, 0, 0);
}

// ---------------- weight transpose + cast: src fp32 [K,N] -> dst bf16 [N,K] ----------------
__global__ __launch_bounds__(256) void transpose_cast(
    const float* __restrict__ src, __hip_bfloat16* __restrict__ dst,
    const int K, const int N, const long sL, const long dL)
{
    __shared__ float tile[32][33];
    const int z = blockIdx.z;
    const float* s = src + (long)z * sL;
    __hip_bfloat16* d = dst + (long)z * dL;
    const int bx = blockIdx.x * 32;   // N block
    const int by = blockIdx.y * 32;   // K block
    const int tx = threadIdx.x, ty = threadIdx.y;
    #pragma unroll
    for (int r = 0; r < 4; ++r)
        tile[ty + r*8][tx] = s[(long)(by + ty + r*8) * N + bx + tx];
    __syncthreads();
    #pragma unroll
    for (int r = 0; r < 4; ++r)
        d[(long)(bx + ty + r*8) * K + by + tx] = __float2bfloat16(tile[tx][ty + r*8]);
}

// ---------------- embedding + sinusoidal PE -> h fp32, hb bf16 ----------------
__global__ __launch_bounds__(256) void embed_k(
    const int* __restrict__ xids, const float* __restrict__ emb,
    float* __restrict__ h, __hip_bfloat16* __restrict__ hb)
{
    const int row = blockIdx.x, t = threadIdx.x;
    const int tok = xids[row];
    const int spos = row & (SEQ - 1);
    const long base = (long)row * D_MODEL;
    const long ebase = (long)tok * D_MODEL;
    #pragma unroll
    for (int j = 0; j < 3; ++j) {
        const int d = j*256 + t;
        const int i = d >> 1;
        const float ang = (float)spos * expf(-(float)(2*i) * (9.210340371976184f / 768.0f));
        const float pe = (d & 1) ? cosf(ang) : sinf(ang);
        const float v = emb[ebase + d] + pe;
        h[base + d] = v;
        hb[base + d] = __float2bfloat16(v);
    }
}

// ---------------- residual add (sum of nplanes partial deltas) + LayerNorm ----------------
__global__ __launch_bounds__(256) void ln_residual(
    float* __restrict__ h, __hip_bfloat16* __restrict__ hb,
    const float* __restrict__ delta,
    const float* __restrict__ sc, const float* __restrict__ bi,
    const int nplanes)
{
    const int row = blockIdx.x, t = threadIdx.x;
    const long base = (long)row * D_MODEL;
    float x[3];
    float s1 = 0.f, s2 = 0.f;
    #pragma unroll
    for (int j = 0; j < 3; ++j) {
        const int d = j*256 + t;
        float v = h[base + d];
        for (int p = 0; p < nplanes; ++p)
            v += delta[(long)p * MROWS * D_MODEL + base + d];
        x[j] = v; s1 += v; s2 += v*v;
    }
    #pragma unroll
    for (int off = 32; off >= 1; off >>= 1) {
        s1 += __shfl_xor(s1, off);
        s2 += __shfl_xor(s2, off);
    }
    __shared__ float r1[4], r2[4];
    const int wv = t >> 6;
    if ((t & 63) == 0) { r1[wv] = s1; r2[wv] = s2; }
    __syncthreads();
    s1 = r1[0] + r1[1] + r1[2] + r1[3];
    s2 = r2[0] + r2[1] + r2[2] + r2[3];
    const float mean = s1 * (1.0f/768.0f);
    const float var  = s2 * (1.0f/768.0f) - mean*mean;
    const float inv  = rsqrtf(var + 1e-5f);
    #pragma unroll
    for (int j = 0; j < 3; ++j) {
        const int d = j*256 + t;
        const float y = (x[j] - mean) * inv * sc[d] + bi[d];
        h[base + d] = y;
        hb[base + d] = __float2bfloat16(y);
    }
}

// ---------------- generic bf16 MFMA GEMM: C[M,N] = A[M,K] * Bt[N,K]^T (+epilogue) ----------------
// 128x128 tile, BK=32, 256 threads (4 waves, 2x2).
// 2-phase double-buffered LDS (T3 minimum): issue next tile's global_load_lds right after
// the barrier, compute current tile, drain at top of next iter. One barrier per K-step.
// Block remap: bijective XCD chunking (m204) + M8-chunk hierarchical order: within a chunk,
// 8 M-blocks fastest, then N. Per-XCD concurrent working set ~1.6MB A + ~2MB B < 4MiB L2;
// B over-fetch 2x instead of 16x (N-major) or L2-thrash (M16-major, round-1 regression).
// Split-K via blockIdx.z: chunk z computes K-range [z*Kc,(z+1)*Kc) and writes fp32 partial
// plane z (EPI_PLAIN / EPI_BIAS only); consumer sums planes. Bias added by plane 0 only.
__global__ __launch_bounds__(256) void gemm_bt(
    const __hip_bfloat16* __restrict__ A,
    const __hip_bfloat16* __restrict__ Bt,
    const float* __restrict__ bias,
    float* __restrict__ outf,
    __hip_bfloat16* __restrict__ outb,
    const int N, const int K, const int epi)
{
    __shared__ __hip_bfloat16 As[2][128*32];
    __shared__ __hip_bfloat16 Bs[2][128*32];
    const int tid = threadIdx.x;
    const int lane = tid & 63, wv = tid >> 6;

    // --- block remap: bijective XCD chunk + M8-fastest within chunk ---
    const int nwg  = gridDim.x * gridDim.y;          // all grids here: nwg % 8 == 0, gridDim.y == 16
    const int orig = blockIdx.y * gridDim.x + blockIdx.x;
    const int qq = nwg >> 3, rr = nwg & 7;
    const int xcd = orig & 7, lin = orig >> 3;
    const int wgid = (xcd < rr ? xcd * (qq + 1) : rr * (qq + 1) + (xcd - rr) * qq) + lin;
    const int m8   = wgid & 7;
    const int rest = wgid >> 3;
    const int bni  = rest % gridDim.x;
    const int bmi  = (rest / gridDim.x) * 8 + m8;
    const int bm = bmi * 128, bn = bni * 128;

    const int wm = (wv >> 1) * 64, wn = (wv & 1) * 64;
    const int fr = lane & 15, fq = lane >> 4;

    // --- split-K ---
    const int Kc = K / gridDim.z;
    const long zoff = (long)blockIdx.z * Kc;

    facc4 acc[4][4];
    #pragma unroll
    for (int i = 0; i < 4; ++i)
        #pragma unroll
        for (int j = 0; j < 4; ++j) { facc4 z = {0.f,0.f,0.f,0.f}; acc[i][j] = z; }

    // staging: wave wv owns tile rows [wv*32, wv*32+32), 2 issues of 16 rows each
    const int srow = wv*32 + (lane >> 2);
    const int scol = (lane & 3) * 8;
    const __hip_bfloat16* Ag = A  + (long)(bm + srow) * K + scol + zoff;
    const __hip_bfloat16* Bg = Bt + (long)(bn + srow) * K + scol + zoff;
    __hip_bfloat16* Aw0 = &As[0][wv*1024];
    __hip_bfloat16* Aw1 = &As[1][wv*1024];
    __hip_bfloat16* Bw0 = &Bs[0][wv*1024];
    __hip_bfloat16* Bw1 = &Bs[1][wv*1024];

    const int nt = Kc >> 5;
    // prologue: stage tile 0 into buffer 0
    gld_lds16(Ag,                 Aw0);
    gld_lds16(Ag + (long)16*K,    Aw0 + 512);
    gld_lds16(Bg,                 Bw0);
    gld_lds16(Bg + (long)16*K,    Bw0 + 512);

    int cur = 0;
    for (int t = 0; t < nt; ++t) {
        __syncthreads();   // drains vmcnt: buf[cur] staged; also fences prev-iter ds_reads
        if (t + 1 < nt) {
            const int k0 = (t + 1) << 5;
            __hip_bfloat16* aw = cur ? Aw0 : Aw1;
            __hip_bfloat16* bw = cur ? Bw0 : Bw1;
            gld_lds16(Ag + k0,              aw);
            gld_lds16(Ag + k0 + (long)16*K, aw + 512);
            gld_lds16(Bg + k0,              bw);
            gld_lds16(Bg + k0 + (long)16*K, bw + 512);
        }
        const __hip_bfloat16* Ab = cur ? &As[1][0] : &As[0][0];
        const __hip_bfloat16* Bb = cur ? &Bs[1][0] : &Bs[0][0];
        bfrag8 af[4], bf[4];
        #pragma unroll
        for (int i = 0; i < 4; ++i) af[i] = *(const bfrag8*)(Ab + (wm + i*16 + fr)*32 + fq*8);
        #pragma unroll
        for (int j = 0; j < 4; ++j) bf[j] = *(const bfrag8*)(Bb + (wn + j*16 + fr)*32 + fq*8);
        #pragma unroll
        for (int i = 0; i < 4; ++i)
            #pragma unroll
            for (int j = 0; j < 4; ++j)
                acc[i][j] = __builtin_amdgcn_mfma_f32_16x16x32_bf16(af[i], bf[j], acc[i][j], 0, 0, 0);
        cur ^= 1;
    }

    // epilogue: C elem (i,j,r): row = bm+wm+i*16+fq*4+r, col = bn+wn+j*16+fr
    if (epi == EPI_QKV) {
        __hip_bfloat16* qo = outb;
        __hip_bfloat16* ko = outb + QKV_PLANE;
        __hip_bfloat16* vo = outb + 2*QKV_PLANE;
        #pragma unroll
        for (int i = 0; i < 4; ++i) {
            #pragma unroll
            for (int j = 0; j < 4; ++j) {
                const int gn = bn + wn + j*16 + fr;
                const int which = gn / D_MODEL;
                const int nn = gn - which * D_MODEL;
                const int hh = nn >> 6, dd = nn & 63;
                #pragma unroll
                for (int r = 0; r < 4; ++r) {
                    const int gm = bm + wm + i*16 + fq*4 + r;
                    const int bidx = gm >> 10, si = gm & (SEQ-1);
                    const long bh = (long)bidx * NHEAD + hh;
                    const __hip_bfloat16 bv = __float2bfloat16(acc[i][j][r]);
                    if (which == 0)      qo[(bh*SEQ + si)*HDIM + dd] = bv;   // Q planar [bh][s][d]
                    else if (which == 1) ko[(bh*SEQ + si)*HDIM + dd] = bv;   // K planar [bh][s][d]
                    else                 vo[(bh*HDIM + dd)*SEQ + si] = bv;   // V transposed [bh][d][s]
                }
            }
        }
    } else if (epi == EPI_GELU_BF16) {
        #pragma unroll
        for (int i = 0; i < 4; ++i)
            #pragma unroll
            for (int j = 0; j < 4; ++j) {
                const int gn = bn + wn + j*16 + fr;
                const float bb = bias[gn];
                #pragma unroll
                for (int r = 0; r < 4; ++r) {
                    const int gm = bm + wm + i*16 + fq*4 + r;
                    const float v = acc[i][j][r] + bb;
                    const float g = 0.5f * v * (1.0f + erff(v * 0.70710678118f));
                    outb[(long)gm * N + gn] = __float2bfloat16(g);
                }
            }
    } else if (epi == EPI_BIAS) {
        float* outz = outf + (long)blockIdx.z * (long)(gridDim.y * 128) * N;
        #pragma unroll
        for (int i = 0; i < 4; ++i)
            #pragma unroll
            for (int j = 0; j < 4; ++j) {
                const int gn = bn + wn + j*16 + fr;
                const float bb = (blockIdx.z == 0) ? bias[gn] : 0.f;
                #pragma unroll
                for (int r = 0; r < 4; ++r) {
                    const int gm = bm + wm + i*16 + fq*4 + r;
                    outz[(long)gm * N + gn] = acc[i][j][r] + bb;
                }
            }
    } else {
        float* outz = outf + (long)blockIdx.z * (long)(gridDim.y * 128) * N;
        #pragma unroll
        for (int i = 0; i < 4; ++i)
            #pragma unroll
            for (int j = 0; j < 4; ++j) {
                const int gn = bn + wn + j*16 + fr;
                #pragma unroll
                for (int r = 0; r < 4; ++r) {
                    const int gm = bm + wm + i*16 + fq*4 + r;
                    outz[(long)gm * N + gn] = acc[i][j][r];
                }
            }
    }
}

// ---------------- fused causal attention (strict mask k<q, exp/(sum+1e-9) softmax) ----------------
// grid (S/64, B*H); block 256 = 4 waves; wave w owns q rows [q0+16w, q0+16w+16)
// T14 async-stage: next K/V tile global loads issued right after this tile's LDS stores,
// HBM latency hides under QK^T+softmax+PV. Ps is wave-private: lgkmcnt(0) replaces barrier 3.
#define KS_STRIDE 80   // 32 k-rows x 64 d, padded (160B rows, 16B aligned)
#define VS_STRIDE 40   // 64 d-rows x 32 k, padded (80B rows)
#define PS_STRIDE 40   // per-wave P: 16 q x 32 k, padded
__global__ __launch_bounds__(256) void attn_flash(
    const __hip_bfloat16* __restrict__ Q,   // [BH][S][64]
    const __hip_bfloat16* __restrict__ Kp,  // [BH][S][64]
    const __hip_bfloat16* __restrict__ Vt,  // [BH][64][S]
    __hip_bfloat16* __restrict__ avo)       // [2048][768] bf16 (A for Wo GEMM)
{
    __shared__ __hip_bfloat16 Ks[32*KS_STRIDE];
    __shared__ __hip_bfloat16 Vs[64*VS_STRIDE];
    __shared__ __hip_bfloat16 Ps[4][16*PS_STRIDE];
    const int tid = threadIdx.x;
    const int lane = tid & 63, wv = tid >> 6;
    const int fr = lane & 15, fq = lane >> 4;
    const int q0 = blockIdx.x * 64;
    const int bh = blockIdx.y;
    const int qrow = q0 + wv*16;

    // Q fragments straight from global (A layout: m=fr, k=fq*8+j)
    const __hip_bfloat16* qp = Q + ((long)bh*SEQ + qrow + fr)*HDIM + fq*8;
    const bfrag8 aq0 = *(const bfrag8*)(qp);
    const bfrag8 aq1 = *(const bfrag8*)(qp + 32);

    facc4 accv[4];
    #pragma unroll
    for (int n = 0; n < 4; ++n) { facc4 z = {0.f,0.f,0.f,0.f}; accv[n] = z; }
    float denom[4] = {0.f, 0.f, 0.f, 0.f};

    const __hip_bfloat16* kg = Kp + ((long)bh*SEQ + (tid>>3))*HDIM + (tid&7)*8;
    const __hip_bfloat16* vg = Vt + ((long)bh*HDIM + (tid>>2))*SEQ + (tid&3)*8;
    __hip_bfloat16* ksw = Ks + (tid>>3)*KS_STRIDE + (tid&7)*8;
    __hip_bfloat16* vsw = Vs + (tid>>2)*VS_STRIDE + (tid&3)*8;

    // prefetch first K/V tile into registers
    bfrag8 kr = *(const bfrag8*)(kg);
    bfrag8 vr = *(const bfrag8*)(vg);

    const int kend = q0 + 64;   // strict mask: max needed k is q0+62
    for (int k0 = 0; k0 < kend; k0 += 32) {
        __syncthreads();                      // prev-iter LDS readers done
        *(bfrag8*)ksw = kr;
        *(bfrag8*)vsw = vr;
        // issue next-tile global loads NOW; latency hides under QK+softmax+PV
        const long knext = (k0 + 32 < kend) ? (long)(k0 + 32) : (long)k0;
        kr = *(const bfrag8*)(kg + knext * HDIM);
        vr = *(const bfrag8*)(vg + knext);
        __syncthreads();                      // K/V stores visible
        #pragma unroll
        for (int t = 0; t < 2; ++t) {
            const int koff = t*16;
            const bfrag8 bk0 = *(const bfrag8*)(Ks + (koff + fr)*KS_STRIDE + fq*8);
            const bfrag8 bk1 = *(const bfrag8*)(Ks + (koff + fr)*KS_STRIDE + 32 + fq*8);
            facc4 sc = {0.f,0.f,0.f,0.f};
            __builtin_amdgcn_s_setprio(1);
            sc = __builtin_amdgcn_mfma_f32_16x16x32_bf16(aq0, bk0, sc, 0, 0, 0);
            sc = __builtin_amdgcn_mfma_f32_16x16x32_bf16(aq1, bk1, sc, 0, 0, 0);
            __builtin_amdgcn_s_setprio(0);
            const int ki = k0 + koff + fr;
            #pragma unroll
            for (int r = 0; r < 4; ++r) {
                const int qi = qrow + fq*4 + r;
                const float e = (ki < qi) ? __expf(sc[r] * 0.125f) : 0.f;
                denom[r] += e;
                Ps[wv][(fq*4 + r)*PS_STRIDE + koff + fr] = __float2bfloat16(e);
            }
        }
        // Ps is wave-private: in-wave DS ordering + lgkmcnt drain is enough (no barrier)
        asm volatile("s_waitcnt lgkmcnt(0)" ::: "memory");
        __builtin_amdgcn_sched_barrier(0);
        const bfrag8 ap = *(const bfrag8*)(&Ps[wv][fr*PS_STRIDE + fq*8]);
        __builtin_amdgcn_s_setprio(1);
        #pragma unroll
        for (int n = 0; n < 4; ++n) {
            const bfrag8 bv = *(const bfrag8*)(Vs + (n*16 + fr)*VS_STRIDE + fq*8);
            accv[n] = __builtin_amdgcn_mfma_f32_16x16x32_bf16(ap, bv, accv[n], 0, 0, 0);
        }
        __builtin_amdgcn_s_setprio(0);
    }

    // row sums: reduce denom across the 16 lanes of each row group
    #pragma unroll
    for (int r = 0; r < 4; ++r) {
        #pragma unroll
        for (int off = 1; off < 16; off <<= 1) denom[r] += __shfl_xor(denom[r], off);
    }
    const int bidx = bh / NHEAD, hh = bh % NHEAD;
    #pragma unroll
    for (int n = 0; n < 4; ++n) {
        #pragma unroll
        for (int r = 0; r < 4; ++r) {
            const int qi = qrow + fq*4 + r;
            const int dd = n*16 + fr;
            const float o = accv[n][r] / (denom[r] + 1e-9f);
            avo[((long)(bidx*SEQ + qi))*D_MODEL + hh*HDIM + dd] = __float2bfloat16(o);
        }
    }
}

extern "C" void kernel_launch(void* const* d_in, const int* in_sizes, int n_in,
                              void* d_out, int out_size, void* d_ws, size_t ws_size,
                              hipStream_t stream) {
    const int*   x    = (const int*)d_in[0];
    const float* emb  = (const float*)d_in[1];
    const float* Wq   = (const float*)d_in[2];
    const float* Wk   = (const float*)d_in[3];
    const float* Wv   = (const float*)d_in[4];
    const float* Wo   = (const float*)d_in[5];
    const float* ln1s = (const float*)d_in[6];
    const float* ln1b = (const float*)d_in[7];
    const float* W1   = (const float*)d_in[8];
    const float* b1   = (const float*)d_in[9];
    const float* W2   = (const float*)d_in[10];
    const float* b2   = (const float*)d_in[11];
    const float* ln2s = (const float*)d_in[12];
    const float* ln2b = (const float*)d_in[13];
    const float* lmW  = (const float*)d_in[14];
    const float* lmb  = (const float*)d_in[15];
    float* out = (float*)d_out;

    char* wsp = (char*)d_ws;
    size_t off = 0;
    auto take = [&](size_t bytes) -> char* {
        char* p = wsp + off;
        off += (bytes + 255) & ~(size_t)255;
        return p;
    };
    __hip_bfloat16* wqkvT = (__hip_bfloat16*)take((size_t)L_LAYERS*2304*768*2); // fused [2304,768] per layer
    __hip_bfloat16* woT   = (__hip_bfloat16*)take((size_t)L_LAYERS*768*768*2);
    __hip_bfloat16* w1T   = (__hip_bfloat16*)take((size_t)L_LAYERS*3072*768*2);
    __hip_bfloat16* w2T   = (__hip_bfloat16*)take((size_t)L_LAYERS*768*3072*2);
    __hip_bfloat16* lmT   = (__hip_bfloat16*)take((size_t)VOCAB*768*2);
    float*          hbuf  = (float*)take((size_t)MROWS*D_MODEL*4);
    __hip_bfloat16* hb    = (__hip_bfloat16*)take((size_t)MROWS*D_MODEL*2);
    __hip_bfloat16* qkvb  = (__hip_bfloat16*)take((size_t)3*QKV_PLANE*2);
    __hip_bfloat16* avb   = (__hip_bfloat16*)take((size_t)MROWS*D_MODEL*2);
    __hip_bfloat16* ffb   = (__hip_bfloat16*)take((size_t)MROWS*DFF_DIM*2);
    float*          tmp   = (float*)take((size_t)4*MROWS*D_MODEL*4);   // 4 split-K planes

    dim3 tb(32, 8);
    transpose_cast<<<dim3(24,24,4), tb, 0, stream>>>(Wq, wqkvT,              768, 768, (long)768*768, (long)2304*768);
    transpose_cast<<<dim3(24,24,4), tb, 0, stream>>>(Wk, wqkvT + 768*768,    768, 768, (long)768*768, (long)2304*768);
    transpose_cast<<<dim3(24,24,4), tb, 0, stream>>>(Wv, wqkvT + 2*768*768,  768, 768, (long)768*768, (long)2304*768);
    transpose_cast<<<dim3(24,24,4), tb, 0, stream>>>(Wo, woT,                768, 768, (long)768*768, (long)768*768);
    transpose_cast<<<dim3(96,24,4), tb, 0, stream>>>(W1, w1T,                768, 3072, (long)768*3072, (long)3072*768);
    transpose_cast<<<dim3(24,96,4), tb, 0, stream>>>(W2, w2T,                3072, 768, (long)3072*768, (long)768*3072);
    transpose_cast<<<dim3(1000,24,1), tb, 0, stream>>>(lmW, lmT,             768, VOCAB, 0, 0);

    embed_k<<<MROWS, 256, 0, stream>>>(x, emb, hbuf, hb);

    for (int l = 0; l < L_LAYERS; ++l) {
        gemm_bt<<<dim3(18,16), 256, 0, stream>>>(hb, wqkvT + (size_t)l*2304*768, nullptr,
                                                 nullptr, qkvb, 2304, 768, EPI_QKV);
        attn_flash<<<dim3(16,24), 256, 0, stream>>>(qkvb, qkvb + QKV_PLANE, qkvb + 2*QKV_PLANE, avb);
        // Wo: split-K x2 (96 -> 192 wg) writing 2 fp32 partial planes
        gemm_bt<<<dim3(6,16,2), 256, 0, stream>>>(avb, woT + (size_t)l*768*768, nullptr,
                                                  tmp, nullptr, 768, 768, EPI_PLAIN);
        ln_residual<<<MROWS, 256, 0, stream>>>(hbuf, hb, tmp, ln1s + l*768, ln1b + l*768, 2);
        gemm_bt<<<dim3(24,16), 256, 0, stream>>>(hb, w1T + (size_t)l*3072*768, b1 + l*DFF_DIM,
                                                 nullptr, ffb, DFF_DIM, 768, EPI_GELU_BF16);
        // FF2: split-K x4 (384 wg, K=768 per block) writing 4 fp32 partial planes
        gemm_bt<<<dim3(6,16,4), 256, 0, stream>>>(ffb, w2T + (size_t)l*768*3072, b2 + l*768,
                                                  tmp, nullptr, 768, DFF_DIM, EPI_BIAS);
        ln_residual<<<MROWS, 256, 0, stream>>>(hbuf, hb, tmp, ln2s + l*768, ln2b + l*768, 4);
    }
    gemm_bt<<<dim3(250,16), 256, 0, stream>>>(hb, lmT, lmb, out, nullptr, VOCAB, 768, EPI_BIAS);
}

// Round 3
// 1161.374 us; speedup vs baseline: 1.2526x; 1.0020x over previous
//
#include <hip/hip_runtime.h>
#include <hip/hip_bf16.h>

#define L_LAYERS 4
#define D_MODEL 768
#define SEQ 1024
#define BATCH 2
#define NHEAD 12
#define HDIM 64
#define DFF_DIM 3072
#define VOCAB 32000
#define MROWS (BATCH*SEQ)                      // 2048
#define QKV_PLANE (NHEAD*BATCH*SEQ*HDIM)       // 24*1024*64 = 1572864

typedef __attribute__((ext_vector_type(8))) short bfrag8;   // 8 bf16 in 4 VGPRs
typedef __attribute__((ext_vector_type(4))) float facc4;    // MFMA accumulator

#define EPI_PLAIN 0
#define EPI_BIAS 1
#define EPI_GELU_BF16 2
#define EPI_QKV 3

__device__ __forceinline__ void gld_lds16(const __hip_bfloat16* g, __hip_bfloat16* l) {
    __builtin_amdgcn_global_load_lds((const __attribute__((address_space(1))) void*)g,
                                     (__attribute__((address_space(3))) void*)l, 16, 0, 0);
}

// ---------------- weight transpose + cast: src fp32 [K,N] -> dst bf16 [N,K] ----------------
__global__ __launch_bounds__(256) void transpose_cast(
    const float* __restrict__ src, __hip_bfloat16* __restrict__ dst,
    const int K, const int N, const long sL, const long dL)
{
    __shared__ float tile[32][33];
    const int z = blockIdx.z;
    const float* s = src + (long)z * sL;
    __hip_bfloat16* d = dst + (long)z * dL;
    const int bx = blockIdx.x * 32;   // N block
    const int by = blockIdx.y * 32;   // K block
    const int tx = threadIdx.x, ty = threadIdx.y;
    #pragma unroll
    for (int r = 0; r < 4; ++r)
        tile[ty + r*8][tx] = s[(long)(by + ty + r*8) * N + bx + tx];
    __syncthreads();
    #pragma unroll
    for (int r = 0; r < 4; ++r)
        d[(long)(bx + ty + r*8) * K + by + tx] = __float2bfloat16(tile[tx][ty + r*8]);
}

// ---------------- embedding + sinusoidal PE -> h fp32, hb bf16 ----------------
__global__ __launch_bounds__(256) void embed_k(
    const int* __restrict__ xids, const float* __restrict__ emb,
    float* __restrict__ h, __hip_bfloat16* __restrict__ hb)
{
    const int row = blockIdx.x, t = threadIdx.x;
    const int tok = xids[row];
    const int spos = row & (SEQ - 1);
    const long base = (long)row * D_MODEL;
    const long ebase = (long)tok * D_MODEL;
    #pragma unroll
    for (int j = 0; j < 3; ++j) {
        const int d = j*256 + t;
        const int i = d >> 1;
        const float ang = (float)spos * expf(-(float)(2*i) * (9.210340371976184f / 768.0f));
        const float pe = (d & 1) ? cosf(ang) : sinf(ang);
        const float v = emb[ebase + d] + pe;
        h[base + d] = v;
        hb[base + d] = __float2bfloat16(v);
    }
}

// ---------------- residual add (sum of nplanes partial deltas) + LayerNorm ----------------
__global__ __launch_bounds__(256) void ln_residual(
    float* __restrict__ h, __hip_bfloat16* __restrict__ hb,
    const float* __restrict__ delta,
    const float* __restrict__ sc, const float* __restrict__ bi,
    const int nplanes)
{
    const int row = blockIdx.x, t = threadIdx.x;
    const long base = (long)row * D_MODEL;
    float x[3];
    float s1 = 0.f, s2 = 0.f;
    #pragma unroll
    for (int j = 0; j < 3; ++j) {
        const int d = j*256 + t;
        float v = h[base + d];
        for (int p = 0; p < nplanes; ++p)
            v += delta[(long)p * MROWS * D_MODEL + base + d];
        x[j] = v; s1 += v; s2 += v*v;
    }
    #pragma unroll
    for (int off = 32; off >= 1; off >>= 1) {
        s1 += __shfl_xor(s1, off);
        s2 += __shfl_xor(s2, off);
    }
    __shared__ float r1[4], r2[4];
    const int wv = t >> 6;
    if ((t & 63) == 0) { r1[wv] = s1; r2[wv] = s2; }
    __syncthreads();
    s1 = r1[0] + r1[1] + r1[2] + r1[3];
    s2 = r2[0] + r2[1] + r2[2] + r2[3];
    const float mean = s1 * (1.0f/768.0f);
    const float var  = s2 * (1.0f/768.0f) - mean*mean;
    const float inv  = rsqrtf(var + 1e-5f);
    #pragma unroll
    for (int j = 0; j < 3; ++j) {
        const int d = j*256 + t;
        const float y = (x[j] - mean) * inv * sc[d] + bi[d];
        h[base + d] = y;
        hb[base + d] = __float2bfloat16(y);
    }
}

// ---------------- generic bf16 MFMA GEMM: C[M,N] = A[M,K] * Bt[N,K]^T (+epilogue) ----------------
// 128x128 tile, BK=32, 256 threads (4 waves, 2x2), 2-phase dbuf. Used for the layer GEMMs
// (grids too small for 256^2 tiles). See gemm256_bias for the lm-head 8-phase kernel.
__global__ __launch_bounds__(256) void gemm_bt(
    const __hip_bfloat16* __restrict__ A,
    const __hip_bfloat16* __restrict__ Bt,
    const float* __restrict__ bias,
    float* __restrict__ outf,
    __hip_bfloat16* __restrict__ outb,
    const int N, const int K, const int epi)
{
    __shared__ __hip_bfloat16 As[2][128*32];
    __shared__ __hip_bfloat16 Bs[2][128*32];
    const int tid = threadIdx.x;
    const int lane = tid & 63, wv = tid >> 6;

    // --- block remap: bijective XCD chunk + M8-fastest within chunk ---
    const int nwg  = gridDim.x * gridDim.y;
    const int orig = blockIdx.y * gridDim.x + blockIdx.x;
    const int qq = nwg >> 3, rr = nwg & 7;
    const int xcd = orig & 7, lin = orig >> 3;
    const int wgid = (xcd < rr ? xcd * (qq + 1) : rr * (qq + 1) + (xcd - rr) * qq) + lin;
    const int m8   = wgid & 7;
    const int rest = wgid >> 3;
    const int bni  = rest % gridDim.x;
    const int bmi  = (rest / gridDim.x) * 8 + m8;
    const int bm = bmi * 128, bn = bni * 128;

    const int wm = (wv >> 1) * 64, wn = (wv & 1) * 64;
    const int fr = lane & 15, fq = lane >> 4;

    // --- split-K ---
    const int Kc = K / gridDim.z;
    const long zoff = (long)blockIdx.z * Kc;

    facc4 acc[4][4];
    #pragma unroll
    for (int i = 0; i < 4; ++i)
        #pragma unroll
        for (int j = 0; j < 4; ++j) { facc4 z = {0.f,0.f,0.f,0.f}; acc[i][j] = z; }

    const int srow = wv*32 + (lane >> 2);
    const int scol = (lane & 3) * 8;
    const __hip_bfloat16* Ag = A  + (long)(bm + srow) * K + scol + zoff;
    const __hip_bfloat16* Bg = Bt + (long)(bn + srow) * K + scol + zoff;
    __hip_bfloat16* Aw0 = &As[0][wv*1024];
    __hip_bfloat16* Aw1 = &As[1][wv*1024];
    __hip_bfloat16* Bw0 = &Bs[0][wv*1024];
    __hip_bfloat16* Bw1 = &Bs[1][wv*1024];

    const int nt = Kc >> 5;
    gld_lds16(Ag,                 Aw0);
    gld_lds16(Ag + (long)16*K,    Aw0 + 512);
    gld_lds16(Bg,                 Bw0);
    gld_lds16(Bg + (long)16*K,    Bw0 + 512);

    int cur = 0;
    for (int t = 0; t < nt; ++t) {
        __syncthreads();
        if (t + 1 < nt) {
            const int k0 = (t + 1) << 5;
            __hip_bfloat16* aw = cur ? Aw0 : Aw1;
            __hip_bfloat16* bw = cur ? Bw0 : Bw1;
            gld_lds16(Ag + k0,              aw);
            gld_lds16(Ag + k0 + (long)16*K, aw + 512);
            gld_lds16(Bg + k0,              bw);
            gld_lds16(Bg + k0 + (long)16*K, bw + 512);
        }
        const __hip_bfloat16* Ab = cur ? &As[1][0] : &As[0][0];
        const __hip_bfloat16* Bb = cur ? &Bs[1][0] : &Bs[0][0];
        bfrag8 af[4], bf[4];
        #pragma unroll
        for (int i = 0; i < 4; ++i) af[i] = *(const bfrag8*)(Ab + (wm + i*16 + fr)*32 + fq*8);
        #pragma unroll
        for (int j = 0; j < 4; ++j) bf[j] = *(const bfrag8*)(Bb + (wn + j*16 + fr)*32 + fq*8);
        #pragma unroll
        for (int i = 0; i < 4; ++i)
            #pragma unroll
            for (int j = 0; j < 4; ++j)
                acc[i][j] = __builtin_amdgcn_mfma_f32_16x16x32_bf16(af[i], bf[j], acc[i][j], 0, 0, 0);
        cur ^= 1;
    }

    if (epi == EPI_QKV) {
        __hip_bfloat16* qo = outb;
        __hip_bfloat16* ko = outb + QKV_PLANE;
        __hip_bfloat16* vo = outb + 2*QKV_PLANE;
        #pragma unroll
        for (int i = 0; i < 4; ++i) {
            #pragma unroll
            for (int j = 0; j < 4; ++j) {
                const int gn = bn + wn + j*16 + fr;
                const int which = gn / D_MODEL;
                const int nn = gn - which * D_MODEL;
                const int hh = nn >> 6, dd = nn & 63;
                #pragma unroll
                for (int r = 0; r < 4; ++r) {
                    const int gm = bm + wm + i*16 + fq*4 + r;
                    const int bidx = gm >> 10, si = gm & (SEQ-1);
                    const long bh = (long)bidx * NHEAD + hh;
                    const __hip_bfloat16 bv = __float2bfloat16(acc[i][j][r]);
                    if (which == 0)      qo[(bh*SEQ + si)*HDIM + dd] = bv;
                    else if (which == 1) ko[(bh*SEQ + si)*HDIM + dd] = bv;
                    else                 vo[(bh*HDIM + dd)*SEQ + si] = bv;
                }
            }
        }
    } else if (epi == EPI_GELU_BF16) {
        #pragma unroll
        for (int i = 0; i < 4; ++i)
            #pragma unroll
            for (int j = 0; j < 4; ++j) {
                const int gn = bn + wn + j*16 + fr;
                const float bb = bias[gn];
                #pragma unroll
                for (int r = 0; r < 4; ++r) {
                    const int gm = bm + wm + i*16 + fq*4 + r;
                    const float v = acc[i][j][r] + bb;
                    const float g = 0.5f * v * (1.0f + erff(v * 0.70710678118f));
                    outb[(long)gm * N + gn] = __float2bfloat16(g);
                }
            }
    } else if (epi == EPI_BIAS) {
        float* outz = outf + (long)blockIdx.z * (long)(gridDim.y * 128) * N;
        #pragma unroll
        for (int i = 0; i < 4; ++i)
            #pragma unroll
            for (int j = 0; j < 4; ++j) {
                const int gn = bn + wn + j*16 + fr;
                const float bb = (blockIdx.z == 0) ? bias[gn] : 0.f;
                #pragma unroll
                for (int r = 0; r < 4; ++r) {
                    const int gm = bm + wm + i*16 + fq*4 + r;
                    outz[(long)gm * N + gn] = acc[i][j][r] + bb;
                }
            }
    } else {
        float* outz = outf + (long)blockIdx.z * (long)(gridDim.y * 128) * N;
        #pragma unroll
        for (int i = 0; i < 4; ++i)
            #pragma unroll
            for (int j = 0; j < 4; ++j) {
                const int gn = bn + wn + j*16 + fr;
                #pragma unroll
                for (int r = 0; r < 4; ++r) {
                    const int gm = bm + wm + i*16 + fq*4 + r;
                    outz[(long)gm * N + gn] = acc[i][j][r];
                }
            }
    }
}

// ---------------- 256x256-tile 8-phase GEMM (T2+T3+T4+T5), lm-head ----------------
// C[M,N] = A[M,K]*Bt[N,K]^T + bias, fp32 out. 512 threads = 8 waves (2M x 4N),
// BK=64, LDS 128KiB (2 dbuf x (A 32KB + B 32KB)).
// LDS layout (per tile, per operand): element (row r, k-slot s of 8 bf16) at
//   r*64 + (s^(r&7))*8   -- XOR swizzle gives conflict-free ds_read_b128
// Staged via global_load_lds with pre-swizzled per-lane GLOBAL source (linear LDS dest,
// rule #21): thread t, pair m stages global row m*64+(t>>3), k-slot (t&7)^((t>>3)&7).
// Schedule per K-tile: 4 phases {ds_read frags | stage pair of kt+1 | barrier |
// lgkmcnt(0) | setprio(1) 16xMFMA setprio(0) | barrier}; ONE counted vmcnt(2)/tile.
__global__ __launch_bounds__(512, 2) void gemm256_bias(
    const __hip_bfloat16* __restrict__ A,   // [M,K]
    const __hip_bfloat16* __restrict__ Bt,  // [N,K]
    const float* __restrict__ bias,
    float* __restrict__ outf,
    const int N, const int K)
{
    __shared__ __hip_bfloat16 ldsA[2][16384];
    __shared__ __hip_bfloat16 ldsB[2][16384];

    const int tid = threadIdx.x;
    const int lane = tid & 63, wv = tid >> 6;
    const int fr = lane & 15, fq = (lane >> 4) & 3;
    const int wr = wv >> 2, wc = wv & 3;

    // bijective XCD remap + M-fastest (nwg % 8 == 0; lm head: 1000)
    const int nwg  = gridDim.x;
    const int cpx  = nwg >> 3;
    const int orig = blockIdx.x;
    const int wgid = (orig & 7) * cpx + (orig >> 3);
    const int bm = (wgid & 7) * 256;
    const int bn = (wgid >> 3) * 256;

    // staging source (pre-swizzled)
    const int trow = tid >> 3;                       // 0..63
    const int sg   = (tid & 7) ^ (trow & 7);         // global k-slot for this lane
    const __hip_bfloat16* Ag = A  + (long)(bm + trow) * K + sg * 8;
    const __hip_bfloat16* Bg = Bt + (long)(bn + trow) * K + sg * 8;

#define STAGE_PAIR(m, kt1, buf) do { \
    gld_lds16(Ag + (long)((m)*64) * K + (kt1)*64, &ldsA[buf][(m)*4096 + wv*512]); \
    gld_lds16(Bg + (long)((m)*64) * K + (kt1)*64, &ldsB[buf][(m)*4096 + wv*512]); \
  } while (0)

    facc4 acc[8][4];
    #pragma unroll
    for (int i = 0; i < 8; ++i)
        #pragma unroll
        for (int j = 0; j < 4; ++j) { facc4 z = {0.f,0.f,0.f,0.f}; acc[i][j] = z; }

    // fragment read bases (swizzled slot offsets, elements)
    const int rowA = wr * 128 + fr;
    const int rowB = wc * 64  + fr;
    const int sx0 = ((fq)     ^ (fr & 7)) * 8;   // kk=0
    const int sx1 = ((4 + fq) ^ (fr & 7)) * 8;   // kk=1

    const int nt = K >> 6;
    // prologue: stage tile 0 -> buf 0
    STAGE_PAIR(0, 0, 0); STAGE_PAIR(1, 0, 0); STAGE_PAIR(2, 0, 0); STAGE_PAIR(3, 0, 0);

    for (int kt = 0; kt < nt; ++kt) {
        const int p = kt & 1;
        const __hip_bfloat16* Ac = ldsA[p];
        const __hip_bfloat16* Bc = ldsB[p];
        const bool pre = (kt + 1 < nt);

        // ---- phase 0: B all (8) + A quad0 (4); stage pair 0; counted vmcnt ----
        if (pre) {
            STAGE_PAIR(0, kt+1, p^1);
            asm volatile("s_waitcnt vmcnt(2)" ::: "memory");
        } else {
            asm volatile("s_waitcnt vmcnt(0)" ::: "memory");
        }
        __builtin_amdgcn_s_barrier();
        bfrag8 b[4][2];
        #pragma unroll
        for (int j = 0; j < 4; ++j) {
            b[j][0] = *(const bfrag8*)(Bc + (rowB + j*16)*64 + sx0);
            b[j][1] = *(const bfrag8*)(Bc + (rowB + j*16)*64 + sx1);
        }
        {
            bfrag8 a[2][2];
            #pragma unroll
            for (int ii = 0; ii < 2; ++ii) {
                a[ii][0] = *(const bfrag8*)(Ac + (rowA + ii*16)*64 + sx0);
                a[ii][1] = *(const bfrag8*)(Ac + (rowA + ii*16)*64 + sx1);
            }
            asm volatile("s_waitcnt lgkmcnt(0)" ::: "memory");
            __builtin_amdgcn_sched_barrier(0);
            __builtin_amdgcn_s_setprio(1);
            #pragma unroll
            for (int jj = 0; jj < 4; ++jj)
                #pragma unroll
                for (int ii = 0; ii < 2; ++ii) {
                    acc[ii][jj] = __builtin_amdgcn_mfma_f32_16x16x32_bf16(a[ii][0], b[jj][0], acc[ii][jj], 0, 0, 0);
                    acc[ii][jj] = __builtin_amdgcn_mfma_f32_16x16x32_bf16(a[ii][1], b[jj][1], acc[ii][jj], 0, 0, 0);
                }
            __builtin_amdgcn_s_setprio(0);
        }
        __builtin_amdgcn_s_barrier();

        // ---- phases 1..3: A quad q; stage pair q ----
        #pragma unroll
        for (int q = 1; q < 4; ++q) {
            bfrag8 a[2][2];
            #pragma unroll
            for (int ii = 0; ii < 2; ++ii) {
                a[ii][0] = *(const bfrag8*)(Ac + (rowA + (q*2+ii)*16)*64 + sx0);
                a[ii][1] = *(const bfrag8*)(Ac + (rowA + (q*2+ii)*16)*64 + sx1);
            }
            if (pre) {
                if (q == 1)      STAGE_PAIR(1, kt+1, p^1);
                else if (q == 2) STAGE_PAIR(2, kt+1, p^1);
                else             STAGE_PAIR(3, kt+1, p^1);
            }
            __builtin_amdgcn_s_barrier();
            asm volatile("s_waitcnt lgkmcnt(0)" ::: "memory");
            __builtin_amdgcn_sched_barrier(0);
            __builtin_amdgcn_s_setprio(1);
            #pragma unroll
            for (int jj = 0; jj < 4; ++jj)
                #pragma unroll
                for (int ii = 0; ii < 2; ++ii) {
                    acc[q*2+ii][jj] = __builtin_amdgcn_mfma_f32_16x16x32_bf16(a[ii][0], b[jj][0], acc[q*2+ii][jj], 0, 0, 0);
                    acc[q*2+ii][jj] = __builtin_amdgcn_mfma_f32_16x16x32_bf16(a[ii][1], b[jj][1], acc[q*2+ii][jj], 0, 0, 0);
                }
            __builtin_amdgcn_s_setprio(0);
            __builtin_amdgcn_s_barrier();
        }
    }
#undef STAGE_PAIR

    // epilogue: C row = bm + wr*128 + i*16 + fq*4 + rr, col = bn + wc*64 + j*16 + fr
    #pragma unroll
    for (int i = 0; i < 8; ++i) {
        const int gm = bm + wr*128 + i*16 + fq*4;
        #pragma unroll
        for (int j = 0; j < 4; ++j) {
            const int gn = bn + wc*64 + j*16 + fr;
            const float bb = bias[gn];
            #pragma unroll
            for (int rr = 0; rr < 4; ++rr)
                outf[(long)(gm + rr) * N + gn] = acc[i][j][rr] + bb;
        }
    }
}

// ---------------- fused causal attention (strict mask k<q, exp/(sum+1e-9) softmax) ----------------
#define KS_STRIDE 80
#define VS_STRIDE 40
#define PS_STRIDE 40
__global__ __launch_bounds__(256) void attn_flash(
    const __hip_bfloat16* __restrict__ Q,   // [BH][S][64]
    const __hip_bfloat16* __restrict__ Kp,  // [BH][S][64]
    const __hip_bfloat16* __restrict__ Vt,  // [BH][64][S]
    __hip_bfloat16* __restrict__ avo)       // [2048][768] bf16 (A for Wo GEMM)
{
    __shared__ __hip_bfloat16 Ks[32*KS_STRIDE];
    __shared__ __hip_bfloat16 Vs[64*VS_STRIDE];
    __shared__ __hip_bfloat16 Ps[4][16*PS_STRIDE];
    const int tid = threadIdx.x;
    const int lane = tid & 63, wv = tid >> 6;
    const int fr = lane & 15, fq = lane >> 4;
    const int q0 = blockIdx.x * 64;
    const int bh = blockIdx.y;
    const int qrow = q0 + wv*16;

    const __hip_bfloat16* qp = Q + ((long)bh*SEQ + qrow + fr)*HDIM + fq*8;
    const bfrag8 aq0 = *(const bfrag8*)(qp);
    const bfrag8 aq1 = *(const bfrag8*)(qp + 32);

    facc4 accv[4];
    #pragma unroll
    for (int n = 0; n < 4; ++n) { facc4 z = {0.f,0.f,0.f,0.f}; accv[n] = z; }
    float denom[4] = {0.f, 0.f, 0.f, 0.f};

    const __hip_bfloat16* kg = Kp + ((long)bh*SEQ + (tid>>3))*HDIM + (tid&7)*8;
    const __hip_bfloat16* vg = Vt + ((long)bh*HDIM + (tid>>2))*SEQ + (tid&3)*8;
    __hip_bfloat16* ksw = Ks + (tid>>3)*KS_STRIDE + (tid&7)*8;
    __hip_bfloat16* vsw = Vs + (tid>>2)*VS_STRIDE + (tid&3)*8;

    bfrag8 kr = *(const bfrag8*)(kg);
    bfrag8 vr = *(const bfrag8*)(vg);

    const int kend = q0 + 64;
    for (int k0 = 0; k0 < kend; k0 += 32) {
        __syncthreads();
        *(bfrag8*)ksw = kr;
        *(bfrag8*)vsw = vr;
        const long knext = (k0 + 32 < kend) ? (long)(k0 + 32) : (long)k0;
        kr = *(const bfrag8*)(kg + knext * HDIM);
        vr = *(const bfrag8*)(vg + knext);
        __syncthreads();
        #pragma unroll
        for (int t = 0; t < 2; ++t) {
            const int koff = t*16;
            const bfrag8 bk0 = *(const bfrag8*)(Ks + (koff + fr)*KS_STRIDE + fq*8);
            const bfrag8 bk1 = *(const bfrag8*)(Ks + (koff + fr)*KS_STRIDE + 32 + fq*8);
            facc4 sc = {0.f,0.f,0.f,0.f};
            __builtin_amdgcn_s_setprio(1);
            sc = __builtin_amdgcn_mfma_f32_16x16x32_bf16(aq0, bk0, sc, 0, 0, 0);
            sc = __builtin_amdgcn_mfma_f32_16x16x32_bf16(aq1, bk1, sc, 0, 0, 0);
            __builtin_amdgcn_s_setprio(0);
            const int ki = k0 + koff + fr;
            #pragma unroll
            for (int r = 0; r < 4; ++r) {
                const int qi = qrow + fq*4 + r;
                const float e = (ki < qi) ? __expf(sc[r] * 0.125f) : 0.f;
                denom[r] += e;
                Ps[wv][(fq*4 + r)*PS_STRIDE + koff + fr] = __float2bfloat16(e);
            }
        }
        asm volatile("s_waitcnt lgkmcnt(0)" ::: "memory");
        __builtin_amdgcn_sched_barrier(0);
        const bfrag8 ap = *(const bfrag8*)(&Ps[wv][fr*PS_STRIDE + fq*8]);
        __builtin_amdgcn_s_setprio(1);
        #pragma unroll
        for (int n = 0; n < 4; ++n) {
            const bfrag8 bv = *(const bfrag8*)(Vs + (n*16 + fr)*VS_STRIDE + fq*8);
            accv[n] = __builtin_amdgcn_mfma_f32_16x16x32_bf16(ap, bv, accv[n], 0, 0, 0);
        }
        __builtin_amdgcn_s_setprio(0);
    }

    #pragma unroll
    for (int r = 0; r < 4; ++r) {
        #pragma unroll
        for (int off = 1; off < 16; off <<= 1) denom[r] += __shfl_xor(denom[r], off);
    }
    const int bidx = bh / NHEAD, hh = bh % NHEAD;
    #pragma unroll
    for (int n = 0; n < 4; ++n) {
        #pragma unroll
        for (int r = 0; r < 4; ++r) {
            const int qi = qrow + fq*4 + r;
            const int dd = n*16 + fr;
            const float o = accv[n][r] / (denom[r] + 1e-9f);
            avo[((long)(bidx*SEQ + qi))*D_MODEL + hh*HDIM + dd] = __float2bfloat16(o);
        }
    }
}

extern "C" void kernel_launch(void* const* d_in, const int* in_sizes, int n_in,
                              void* d_out, int out_size, void* d_ws, size_t ws_size,
                              hipStream_t stream) {
    const int*   x    = (const int*)d_in[0];
    const float* emb  = (const float*)d_in[1];
    const float* Wq   = (const float*)d_in[2];
    const float* Wk   = (const float*)d_in[3];
    const float* Wv   = (const float*)d_in[4];
    const float* Wo   = (const float*)d_in[5];
    const float* ln1s = (const float*)d_in[6];
    const float* ln1b = (const float*)d_in[7];
    const float* W1   = (const float*)d_in[8];
    const float* b1   = (const float*)d_in[9];
    const float* W2   = (const float*)d_in[10];
    const float* b2   = (const float*)d_in[11];
    const float* ln2s = (const float*)d_in[12];
    const float* ln2b = (const float*)d_in[13];
    const float* lmW  = (const float*)d_in[14];
    const float* lmb  = (const float*)d_in[15];
    float* out = (float*)d_out;

    char* wsp = (char*)d_ws;
    size_t off = 0;
    auto take = [&](size_t bytes) -> char* {
        char* p = wsp + off;
        off += (bytes + 255) & ~(size_t)255;
        return p;
    };
    __hip_bfloat16* wqkvT = (__hip_bfloat16*)take((size_t)L_LAYERS*2304*768*2);
    __hip_bfloat16* woT   = (__hip_bfloat16*)take((size_t)L_LAYERS*768*768*2);
    __hip_bfloat16* w1T   = (__hip_bfloat16*)take((size_t)L_LAYERS*3072*768*2);
    __hip_bfloat16* w2T   = (__hip_bfloat16*)take((size_t)L_LAYERS*768*3072*2);
    __hip_bfloat16* lmT   = (__hip_bfloat16*)take((size_t)VOCAB*768*2);
    float*          hbuf  = (float*)take((size_t)MROWS*D_MODEL*4);
    __hip_bfloat16* hb    = (__hip_bfloat16*)take((size_t)MROWS*D_MODEL*2);
    __hip_bfloat16* qkvb  = (__hip_bfloat16*)take((size_t)3*QKV_PLANE*2);
    __hip_bfloat16* avb   = (__hip_bfloat16*)take((size_t)MROWS*D_MODEL*2);
    __hip_bfloat16* ffb   = (__hip_bfloat16*)take((size_t)MROWS*DFF_DIM*2);
    float*          tmp   = (float*)take((size_t)4*MROWS*D_MODEL*4);   // 4 split-K planes

    dim3 tb(32, 8);
    transpose_cast<<<dim3(24,24,4), tb, 0, stream>>>(Wq, wqkvT,              768, 768, (long)768*768, (long)2304*768);
    transpose_cast<<<dim3(24,24,4), tb, 0, stream>>>(Wk, wqkvT + 768*768,    768, 768, (long)768*768, (long)2304*768);
    transpose_cast<<<dim3(24,24,4), tb, 0, stream>>>(Wv, wqkvT + 2*768*768,  768, 768, (long)768*768, (long)2304*768);
    transpose_cast<<<dim3(24,24,4), tb, 0, stream>>>(Wo, woT,                768, 768, (long)768*768, (long)768*768);
    transpose_cast<<<dim3(96,24,4), tb, 0, stream>>>(W1, w1T,                768, 3072, (long)768*3072, (long)3072*768);
    transpose_cast<<<dim3(24,96,4), tb, 0, stream>>>(W2, w2T,                3072, 768, (long)3072*768, (long)768*3072);
    transpose_cast<<<dim3(1000,24,1), tb, 0, stream>>>(lmW, lmT,             768, VOCAB, 0, 0);

    embed_k<<<MROWS, 256, 0, stream>>>(x, emb, hbuf, hb);

    for (int l = 0; l < L_LAYERS; ++l) {
        gemm_bt<<<dim3(18,16), 256, 0, stream>>>(hb, wqkvT + (size_t)l*2304*768, nullptr,
                                                 nullptr, qkvb, 2304, 768, EPI_QKV);
        attn_flash<<<dim3(16,24), 256, 0, stream>>>(qkvb, qkvb + QKV_PLANE, qkvb + 2*QKV_PLANE, avb);
        gemm_bt<<<dim3(6,16,2), 256, 0, stream>>>(avb, woT + (size_t)l*768*768, nullptr,
                                                  tmp, nullptr, 768, 768, EPI_PLAIN);
        ln_residual<<<MROWS, 256, 0, stream>>>(hbuf, hb, tmp, ln1s + l*768, ln1b + l*768, 2);
        gemm_bt<<<dim3(24,16), 256, 0, stream>>>(hb, w1T + (size_t)l*3072*768, b1 + l*DFF_DIM,
                                                 nullptr, ffb, DFF_DIM, 768, EPI_GELU_BF16);
        gemm_bt<<<dim3(6,16,4), 256, 0, stream>>>(ffb, w2T + (size_t)l*768*3072, b2 + l*768,
                                                  tmp, nullptr, 768, DFF_DIM, EPI_BIAS);
        ln_residual<<<MROWS, 256, 0, stream>>>(hbuf, hb, tmp, ln2s + l*768, ln2b + l*768, 4);
    }
    // lm head: 256^2 8-phase kernel, grid 125x8 = 1000 blocks
    gemm256_bias<<<1000, 512, 0, stream>>>(hb, lmT, lmb, out, VOCAB, 768);
}